// Round 1
// baseline (438.799 us; speedup 1.0000x reference)
//
#include <hip/hip_runtime.h>
#include <hip/hip_bf16.h>
#include <math.h>

#define S_LEN 2048
#define H_DIM 1024
#define NHEAD 16
#define HD 64
#define NMEM 4
#define NCHUNK 32
#define CLEN 64
#define EPS_C 1e-6f

// ---------------------------------------------------------------------------
// GEMM: C[m,n] = act( sum_k A[m,k] * B[n,k] )   (A: MxK row-major, B: NxK row-major)
// ACT=0: none, ACT=1: elu(x)+1 = x>0 ? x+1 : exp(x)
// 64x64 block tile, 256 threads, 4x4 microtile, K-major LDS tiles.
// ---------------------------------------------------------------------------
template <int ACT>
__global__ __launch_bounds__(256) void gemm_bt_kernel(const float* __restrict__ A,
                                                      const float* __restrict__ B,
                                                      float* __restrict__ C,
                                                      int M, int N, int K) {
    __shared__ float As[16][68];
    __shared__ float Bs[16][68];
    const int tid = threadIdx.x;
    const int tx = tid & 15, ty = tid >> 4;
    const int bm = blockIdx.x * 64, bn = blockIdx.y * 64;
    const int lr = tid >> 2;          // 0..63: tile row to load
    const int lc = (tid & 3) * 4;     // k-subgroup
    float acc[4][4] = {};
    const float* Aptr = A + (size_t)(bm + lr) * K + lc;
    const float* Bptr = B + (size_t)(bn + lr) * K + lc;
    for (int k0 = 0; k0 < K; k0 += 16) {
        float4 av = *(const float4*)(Aptr + k0);
        float4 bv = *(const float4*)(Bptr + k0);
        __syncthreads();
        As[lc + 0][lr] = av.x; As[lc + 1][lr] = av.y;
        As[lc + 2][lr] = av.z; As[lc + 3][lr] = av.w;
        Bs[lc + 0][lr] = bv.x; Bs[lc + 1][lr] = bv.y;
        Bs[lc + 2][lr] = bv.z; Bs[lc + 3][lr] = bv.w;
        __syncthreads();
#pragma unroll
        for (int kk = 0; kk < 16; ++kk) {
            float4 a = *(const float4*)&As[kk][ty * 4];
            float4 b = *(const float4*)&Bs[kk][tx * 4];
            float ar[4] = {a.x, a.y, a.z, a.w};
            float br[4] = {b.x, b.y, b.z, b.w};
#pragma unroll
            for (int i = 0; i < 4; ++i)
#pragma unroll
                for (int j = 0; j < 4; ++j)
                    acc[i][j] = fmaf(ar[i], br[j], acc[i][j]);
        }
    }
#pragma unroll
    for (int i = 0; i < 4; ++i) {
        const int row = bm + ty * 4 + i;
#pragma unroll
        for (int j = 0; j < 4; ++j) {
            const int col = bn + tx * 4 + j;
            float x = acc[i][j];
            if (ACT == 1) x = (x > 0.f) ? (x + 1.f) : __expf(x);
            C[(size_t)row * N + col] = x;
        }
    }
}

// ---------------------------------------------------------------------------
// rel[m,h,s] = sum_d sq[s, h*64+d] * norms[m,h,d];  relsum[m,h] = sum_s rel
// grid: NMEM*NHEAD blocks, 256 threads
// ---------------------------------------------------------------------------
__global__ __launch_bounds__(256) void rel_kernel(const float* __restrict__ sq,
                                                  const float* __restrict__ norms,
                                                  float* __restrict__ rel,
                                                  float* __restrict__ relsum) {
    const int m = blockIdx.x >> 4;
    const int h = blockIdx.x & 15;
    __shared__ float nl[64];
    __shared__ float red[256];
    const int tid = threadIdx.x;
    if (tid < 64) nl[tid] = norms[(size_t)(m * NHEAD + h) * HD + tid];
    __syncthreads();
    float lsum = 0.f;
    for (int s = tid; s < S_LEN; s += 256) {
        const float* row = sq + (size_t)s * H_DIM + h * HD;
        float dot = 0.f;
#pragma unroll
        for (int d = 0; d < 64; d += 4) {
            float4 v = *(const float4*)(row + d);
            dot += v.x * nl[d] + v.y * nl[d + 1] + v.z * nl[d + 2] + v.w * nl[d + 3];
        }
        rel[(size_t)(m * NHEAD + h) * S_LEN + s] = dot;
        lsum += dot;
    }
    red[tid] = lsum;
    __syncthreads();
    for (int o = 128; o > 0; o >>= 1) {
        if (tid < o) red[tid] += red[tid + o];
        __syncthreads();
    }
    if (tid == 0) relsum[m * NHEAD + h] = red[0];
}

// ---------------------------------------------------------------------------
// weights[m,h] = softmax over m of (relsum[m,h]/S)
// ---------------------------------------------------------------------------
__global__ void weights_kernel(const float* __restrict__ relsum,
                               float* __restrict__ weights) {
    const int h = threadIdx.x;
    if (h >= NHEAD) return;
    float v[NMEM];
    float mx = -1e30f;
#pragma unroll
    for (int m = 0; m < NMEM; ++m) {
        v[m] = relsum[m * NHEAD + h] / (float)S_LEN;
        mx = fmaxf(mx, v[m]);
    }
    float sum = 0.f;
#pragma unroll
    for (int m = 0; m < NMEM; ++m) { v[m] = __expf(v[m] - mx); sum += v[m]; }
#pragma unroll
    for (int m = 0; m < NMEM; ++m) weights[m * NHEAD + h] = v[m] / sum;
}

// ---------------------------------------------------------------------------
// combined[s, h*64+e] = g[h] * sum_m (w[m,h]/max(rel[m,h,s],EPS)) * sum_d sq[s,d]*mem[m,h,d,e]
// grid: (NHEAD, S/64), 256 threads
// ---------------------------------------------------------------------------
__global__ __launch_bounds__(256) void memout_kernel(const float* __restrict__ sq,
                                                     const float* __restrict__ memories,
                                                     const float* __restrict__ rel,
                                                     const float* __restrict__ weights,
                                                     const float* __restrict__ gate,
                                                     float* __restrict__ combined) {
    const int h = blockIdx.x;
    const int sbase = blockIdx.y * 64;
    __shared__ float mem_s[NMEM][64][64];
    __shared__ float sqrow[4][64];
    const int tid = threadIdx.x;
#pragma unroll
    for (int m = 0; m < NMEM; ++m) {
        const float* src = memories + (size_t)(m * NHEAD + h) * HD * HD;
        float* dst = &mem_s[m][0][0];
#pragma unroll
        for (int j = 0; j < 4; ++j)
            *(float4*)(dst + j * 1024 + tid * 4) = *(const float4*)(src + j * 1024 + tid * 4);
    }
    float w_h[NMEM];
#pragma unroll
    for (int m = 0; m < NMEM; ++m) w_h[m] = weights[m * NHEAD + h];
    const float g = 1.f / (1.f + __expf(-gate[h]));
    const int e = tid & 63;
    const int sl = tid >> 6;
    for (int s0 = 0; s0 < 64; s0 += 4) {
        const int s = sbase + s0 + sl;
        __syncthreads();
        sqrow[sl][e] = sq[(size_t)s * H_DIM + h * HD + e];
        __syncthreads();
        float acc = 0.f;
#pragma unroll
        for (int m = 0; m < NMEM; ++m) {
            const float r = rel[(size_t)(m * NHEAD + h) * S_LEN + s];
            const float cm = w_h[m] / fmaxf(r, EPS_C);
            float part = 0.f;
#pragma unroll
            for (int d = 0; d < 64; ++d)
                part = fmaf(sqrow[sl][d], mem_s[m][d][e], part);
            acc = fmaf(cm, part, acc);
        }
        combined[(size_t)s * H_DIM + h * HD + e] = g * acc;
    }
}

// ---------------------------------------------------------------------------
// Per-chunk KV state: ckv[h,c,d,e] = sum_{s in chunk} sk[s,d]*v[s,e]
//                     cks[h,c,d]   = sum_{s in chunk} sk[s,d]
// grid: (NHEAD, NCHUNK), 256 threads
// ---------------------------------------------------------------------------
__global__ __launch_bounds__(256) void chunkkv_kernel(const float* __restrict__ sk,
                                                      const float* __restrict__ v,
                                                      float* __restrict__ ckv,
                                                      float* __restrict__ cks) {
    const int h = blockIdx.x;
    const int c = blockIdx.y;
    const int s0 = c * CLEN;
    __shared__ float sks[64][64];
    __shared__ float vs[64][64];
    const int tid = threadIdx.x;
#pragma unroll
    for (int j = 0; j < 4; ++j) {
        const int idx = j * 1024 + tid * 4;
        const int r = idx >> 6, cc = idx & 63;
        *(float4*)&sks[r][cc] = *(const float4*)&sk[(size_t)(s0 + r) * H_DIM + h * HD + cc];
        *(float4*)&vs[r][cc]  = *(const float4*)&v[(size_t)(s0 + r) * H_DIM + h * HD + cc];
    }
    __syncthreads();
    const int e = tid & 63;
    const int db = (tid >> 6) * 16;
    float acc[16] = {};
    for (int s = 0; s < 64; ++s) {
        const float vv = vs[s][e];
#pragma unroll
        for (int i = 0; i < 16; ++i) acc[i] = fmaf(sks[s][db + i], vv, acc[i]);
    }
    float* outp = ckv + (size_t)(h * NCHUNK + c) * HD * HD;
#pragma unroll
    for (int i = 0; i < 16; ++i) outp[(db + i) * 64 + e] = acc[i];
    if (tid < 64) {
        float ks = 0.f;
        for (int s = 0; s < 64; ++s) ks += sks[s][tid];
        cks[(size_t)(h * NCHUNK + c) * HD + tid] = ks;
    }
}

// ---------------------------------------------------------------------------
// In-place exclusive prefix over chunks (per head). grid: NHEAD, 256 threads
// ---------------------------------------------------------------------------
__global__ __launch_bounds__(256) void prefix_kernel(float* __restrict__ ckv,
                                                     float* __restrict__ cks) {
    const int h = blockIdx.x;
    const int tid = threadIdx.x;
    const int base = tid * 16;
    float run[16];
#pragma unroll
    for (int i = 0; i < 16; ++i) run[i] = 0.f;
    for (int c = 0; c < NCHUNK; ++c) {
        float* p = ckv + (size_t)(h * NCHUNK + c) * 4096 + base;
#pragma unroll
        for (int i = 0; i < 16; ++i) {
            const float cur = p[i];
            p[i] = run[i];
            run[i] += cur;
        }
    }
    if (tid < 64) {
        float rk = 0.f;
        for (int c = 0; c < NCHUNK; ++c) {
            float* p = cks + (size_t)(h * NCHUNK + c) * HD + tid;
            const float cur = *p;
            *p = rk;
            rk += cur;
        }
    }
}

// ---------------------------------------------------------------------------
// Causal linear attention output for one (head, chunk):
//   num[s,e] = sum_d sq[s,d]*KVpre[d,e] + sum_{t<=s} (sq[s]·sk[t]) v[t,e]
//   den[s]   = max(sum_d sq[s,d]*kpre[d] + sum_{t<=s} sq[s]·sk[t], EPS)
//   combined[s, h*64+e] += (1-g) * num/den
// grid: (NHEAD, NCHUNK), 256 threads
// ---------------------------------------------------------------------------
__global__ __launch_bounds__(256) void attnout_kernel(const float* __restrict__ sq,
                                                      const float* __restrict__ sk,
                                                      const float* __restrict__ v,
                                                      const float* __restrict__ ckv,
                                                      const float* __restrict__ cks,
                                                      const float* __restrict__ gate,
                                                      float* __restrict__ combined) {
    const int h = blockIdx.x;
    const int c = blockIdx.y;
    const int s0 = c * CLEN;
    __shared__ float sqs[64][64], sks[64][64], vs[64][64], kvp[64][64], Am[64][64];
    __shared__ float kp[64], den[64];
    const int tid = threadIdx.x;
    const float* kvsrc = ckv + (size_t)(h * NCHUNK + c) * 4096;
#pragma unroll
    for (int j = 0; j < 4; ++j) {
        const int idx = j * 1024 + tid * 4;
        const int r = idx >> 6, cc = idx & 63;
        *(float4*)&sqs[r][cc] = *(const float4*)&sq[(size_t)(s0 + r) * H_DIM + h * HD + cc];
        *(float4*)&sks[r][cc] = *(const float4*)&sk[(size_t)(s0 + r) * H_DIM + h * HD + cc];
        *(float4*)&vs[r][cc]  = *(const float4*)&v[(size_t)(s0 + r) * H_DIM + h * HD + cc];
        *(float4*)(&kvp[0][0] + idx) = *(const float4*)(kvsrc + idx);
    }
    if (tid < 64) kp[tid] = cks[(size_t)(h * NCHUNK + c) * HD + tid];
    __syncthreads();

    // Phase 1: A[s,t] = sq[s]·sk[t] for t<=s (0 otherwise)
    const int s_a = tid >> 2;
    const int tb = (tid & 3) * 16;
#pragma unroll
    for (int i = 0; i < 16; ++i) {
        const int t = tb + i;
        float dot = 0.f;
        if (t <= s_a) {
#pragma unroll
            for (int d = 0; d < 64; ++d)
                dot = fmaf(sqs[s_a][d], sks[t][d], dot);
        }
        Am[s_a][t] = dot;
    }
    __syncthreads();
    if (tid < 64) {
        float rs = 0.f;
        for (int t = 0; t <= tid; ++t) rs += Am[tid][t];
        float dq = 0.f;
#pragma unroll
        for (int d = 0; d < 64; ++d) dq = fmaf(sqs[tid][d], kp[d], dq);
        den[tid] = fmaxf(dq + rs, EPS_C);
    }
    __syncthreads();

    // Phase 2: outputs
    const int e = tid & 63;
    const int sb = (tid >> 6) * 16;
    const float g = 1.f / (1.f + __expf(-gate[h]));
    const float gl = 1.f - g;
#pragma unroll
    for (int i = 0; i < 16; ++i) {
        const int s = sb + i;
        float num = 0.f;
#pragma unroll
        for (int d = 0; d < 64; ++d)
            num = fmaf(sqs[s][d], kvp[d][e], num);
        for (int t = 0; t <= s; ++t)
            num = fmaf(Am[s][t], vs[t][e], num);
        const size_t oidx = (size_t)(s0 + s) * H_DIM + h * HD + e;
        combined[oidx] += gl * num / den[s];
    }
}

extern "C" void kernel_launch(void* const* d_in, const int* in_sizes, int n_in,
                              void* d_out, int out_size, void* d_ws, size_t ws_size,
                              hipStream_t stream) {
    const float* hidden   = (const float*)d_in[0];
    const float* w_q      = (const float*)d_in[1];
    const float* w_k      = (const float*)d_in[2];
    const float* w_v      = (const float*)d_in[3];
    const float* w_o      = (const float*)d_in[4];
    const float* gate     = (const float*)d_in[5];
    const float* memories = (const float*)d_in[6];
    const float* memnorms = (const float*)d_in[7];
    float* out = (float*)d_out;

    float* ws = (float*)d_ws;
    size_t off = 0;
    float* sq       = ws + off; off += (size_t)S_LEN * H_DIM;
    float* sk       = ws + off; off += (size_t)S_LEN * H_DIM;
    float* vv       = ws + off; off += (size_t)S_LEN * H_DIM;
    float* combined = ws + off; off += (size_t)S_LEN * H_DIM;
    float* rel      = ws + off; off += (size_t)NMEM * NHEAD * S_LEN;
    float* relsum   = ws + off; off += NMEM * NHEAD;
    float* weights  = ws + off; off += NMEM * NHEAD;
    float* ckv      = ws + off; off += (size_t)NHEAD * NCHUNK * HD * HD;
    float* cks      = ws + off; off += (size_t)NHEAD * NCHUNK * HD;

    dim3 gg(S_LEN / 64, H_DIM / 64);
    gemm_bt_kernel<1><<<gg, 256, 0, stream>>>(hidden, w_q, sq, S_LEN, H_DIM, H_DIM);
    gemm_bt_kernel<1><<<gg, 256, 0, stream>>>(hidden, w_k, sk, S_LEN, H_DIM, H_DIM);
    gemm_bt_kernel<0><<<gg, 256, 0, stream>>>(hidden, w_v, vv, S_LEN, H_DIM, H_DIM);
    rel_kernel<<<NMEM * NHEAD, 256, 0, stream>>>(sq, memnorms, rel, relsum);
    weights_kernel<<<1, 64, 0, stream>>>(relsum, weights);
    memout_kernel<<<dim3(NHEAD, S_LEN / 64), 256, 0, stream>>>(sq, memories, rel, weights, gate, combined);
    chunkkv_kernel<<<dim3(NHEAD, NCHUNK), 256, 0, stream>>>(sk, vv, ckv, cks);
    prefix_kernel<<<NHEAD, 256, 0, stream>>>(ckv, cks);
    attnout_kernel<<<dim3(NHEAD, NCHUNK), 256, 0, stream>>>(sq, sk, vv, ckv, cks, gate, combined);
    gemm_bt_kernel<0><<<gg, 256, 0, stream>>>(combined, w_o, out, S_LEN, H_DIM, H_DIM);
}

// Round 2
// 250.334 us; speedup vs baseline: 1.7529x; 1.7529x over previous
//
#include <hip/hip_runtime.h>
#include <hip/hip_bf16.h>
#include <math.h>

#define S_LEN 2048
#define H_DIM 1024
#define NHEAD 16
#define HD 64
#define NMEM 4
#define NCHUNK 32
#define CLEN 64
#define EPS_C 1e-6f

typedef __attribute__((ext_vector_type(8))) short bf16x8;
typedef __attribute__((ext_vector_type(4))) float f32x4;
typedef __attribute__((ext_vector_type(8))) unsigned short u16x8;

__device__ __forceinline__ unsigned short f2bf(float f) {
    unsigned int u = __float_as_uint(f);
    u += 0x7FFFu + ((u >> 16) & 1u);   // round-to-nearest-even
    return (unsigned short)(u >> 16);
}

// ---------------------------------------------------------------------------
// f32 -> bf16 conversion, 8 elems/thread, vectorized
// ---------------------------------------------------------------------------
__global__ __launch_bounds__(256) void cvt_bf16_kernel(const float* __restrict__ in,
                                                       unsigned short* __restrict__ out) {
    const int i = (blockIdx.x * 256 + threadIdx.x) * 8;
    float4 a = *(const float4*)(in + i);
    float4 b = *(const float4*)(in + i + 4);
    u16x8 o;
    o[0] = f2bf(a.x); o[1] = f2bf(a.y); o[2] = f2bf(a.z); o[3] = f2bf(a.w);
    o[4] = f2bf(b.x); o[5] = f2bf(b.y); o[6] = f2bf(b.z); o[7] = f2bf(b.w);
    *(u16x8*)(out + i) = o;
}

// ---------------------------------------------------------------------------
// MFMA bf16 GEMM: C[m,n] = sum_k A[m,k]*B[n,k]  (A: MxK, B: NxK, both row-major bf16)
// 128x128 block tile, 256 threads (4 waves, each 64x64), BK=32,
// global_load_lds staging, 2-barrier K-loop (m97 structure).
// MODE 0: single f32 output d0 (no act), N-stride 1024.
// MODE 1: qkv fused — col segment 0->d0(elu1), 1->d1(elu1), 2->d2(none), stride 1024.
// ---------------------------------------------------------------------------
template <int MODE>
__global__ __launch_bounds__(256) void gemm_mfma_kernel(const unsigned short* __restrict__ A,
                                                        const unsigned short* __restrict__ B,
                                                        float* __restrict__ d0,
                                                        float* __restrict__ d1,
                                                        float* __restrict__ d2,
                                                        int K) {
    __shared__ unsigned short Als[128][32];
    __shared__ unsigned short Bls[128][32];
    const int tid  = threadIdx.x;
    const int lane = tid & 63;
    const int wv   = tid >> 6;          // 0..3
    const int wr   = wv >> 1;           // wave row (0..1)
    const int wc   = wv & 1;            // wave col (0..1)
    const int bm   = blockIdx.x * 128;
    const int bn   = blockIdx.y * 128;

    // staging address components (per lane)
    const int srow = (wv << 5) + (lane >> 2);   // wave's 32-row band, chunk-0 row
    const int skc  = (lane & 3) << 3;           // k offset in elements
    const unsigned short* gA = A + (size_t)(bm + srow) * K + skc;
    const unsigned short* gB = B + (size_t)(bn + srow) * K + skc;

    // fragment read components
    const int frow = lane & 15;
    const int fkof = (lane >> 4) << 3;          // 0,8,16,24 elements

    f32x4 acc[4][4] = {};

    for (int k0 = 0; k0 < K; k0 += 32) {
        __syncthreads();   // previous iteration's readers done
        // stage A,B tiles: 2 chunks of 16 rows each per wave per matrix
        __builtin_amdgcn_global_load_lds(
            (const __attribute__((address_space(1))) void*)(gA + k0),
            (__attribute__((address_space(3))) void*)&Als[(wv << 5)][0], 16, 0, 0);
        __builtin_amdgcn_global_load_lds(
            (const __attribute__((address_space(1))) void*)(gA + k0 + 16 * (size_t)K),
            (__attribute__((address_space(3))) void*)&Als[(wv << 5) + 16][0], 16, 0, 0);
        __builtin_amdgcn_global_load_lds(
            (const __attribute__((address_space(1))) void*)(gB + k0),
            (__attribute__((address_space(3))) void*)&Bls[(wv << 5)][0], 16, 0, 0);
        __builtin_amdgcn_global_load_lds(
            (const __attribute__((address_space(1))) void*)(gB + k0 + 16 * (size_t)K),
            (__attribute__((address_space(3))) void*)&Bls[(wv << 5) + 16][0], 16, 0, 0);
        __syncthreads();   // implicit vmcnt(0) drain before barrier

        bf16x8 af[4], bf[4];
#pragma unroll
        for (int mi = 0; mi < 4; ++mi)
            af[mi] = *(const bf16x8*)&Als[wr * 64 + mi * 16 + frow][fkof];
#pragma unroll
        for (int ni = 0; ni < 4; ++ni)
            bf[ni] = *(const bf16x8*)&Bls[wc * 64 + ni * 16 + frow][fkof];
#pragma unroll
        for (int mi = 0; mi < 4; ++mi)
#pragma unroll
            for (int ni = 0; ni < 4; ++ni)
                acc[mi][ni] = __builtin_amdgcn_mfma_f32_16x16x32_bf16(af[mi], bf[ni], acc[mi][ni], 0, 0, 0);
    }

    // epilogue
    float* dst;
    int colbase;
    bool act = false;
    if (MODE == 1) {
        const int seg = bn >> 10;          // uniform per block (128 | 1024)
        dst = (seg == 0) ? d0 : ((seg == 1) ? d1 : d2);
        colbase = bn & 1023;
        act = (seg < 2);
    } else {
        dst = d0;
        colbase = bn;
    }
    const int crow = (lane >> 4) << 2;
    const int ccol = lane & 15;
#pragma unroll
    for (int mi = 0; mi < 4; ++mi) {
#pragma unroll
        for (int ni = 0; ni < 4; ++ni) {
            const int col = colbase + wc * 64 + ni * 16 + ccol;
#pragma unroll
            for (int r = 0; r < 4; ++r) {
                const int row = bm + wr * 64 + mi * 16 + crow + r;
                float x = acc[mi][ni][r];
                if (MODE == 1 && act) x = (x > 0.f) ? (x + 1.f) : __expf(x);
                dst[(size_t)row * 1024 + col] = x;
            }
        }
    }
}

// ---------------------------------------------------------------------------
// rel[m,h,s] = sum_d sq[s, h*64+d] * norms[m,h,d];  relsum[m,h] = sum_s rel
// ---------------------------------------------------------------------------
__global__ __launch_bounds__(256) void rel_kernel(const float* __restrict__ sq,
                                                  const float* __restrict__ norms,
                                                  float* __restrict__ rel,
                                                  float* __restrict__ relsum) {
    const int m = blockIdx.x >> 4;
    const int h = blockIdx.x & 15;
    __shared__ float nl[64];
    __shared__ float red[256];
    const int tid = threadIdx.x;
    if (tid < 64) nl[tid] = norms[(size_t)(m * NHEAD + h) * HD + tid];
    __syncthreads();
    float lsum = 0.f;
    for (int s = tid; s < S_LEN; s += 256) {
        const float* row = sq + (size_t)s * H_DIM + h * HD;
        float dot = 0.f;
#pragma unroll
        for (int d = 0; d < 64; d += 4) {
            float4 v = *(const float4*)(row + d);
            dot += v.x * nl[d] + v.y * nl[d + 1] + v.z * nl[d + 2] + v.w * nl[d + 3];
        }
        rel[(size_t)(m * NHEAD + h) * S_LEN + s] = dot;
        lsum += dot;
    }
    red[tid] = lsum;
    __syncthreads();
    for (int o = 128; o > 0; o >>= 1) {
        if (tid < o) red[tid] += red[tid + o];
        __syncthreads();
    }
    if (tid == 0) relsum[m * NHEAD + h] = red[0];
}

__global__ void weights_kernel(const float* __restrict__ relsum,
                               float* __restrict__ weights) {
    const int h = threadIdx.x;
    if (h >= NHEAD) return;
    float v[NMEM];
    float mx = -1e30f;
#pragma unroll
    for (int m = 0; m < NMEM; ++m) {
        v[m] = relsum[m * NHEAD + h] / (float)S_LEN;
        mx = fmaxf(mx, v[m]);
    }
    float sum = 0.f;
#pragma unroll
    for (int m = 0; m < NMEM; ++m) { v[m] = __expf(v[m] - mx); sum += v[m]; }
#pragma unroll
    for (int m = 0; m < NMEM; ++m) weights[m * NHEAD + h] = v[m] / sum;
}

// ---------------------------------------------------------------------------
// combined[s, h*64+e] = g[h] * sum_m (w[m,h]/max(rel[m,h,s],EPS)) * sum_d sq[s,d]*mem[m,h,d,e]
// ---------------------------------------------------------------------------
__global__ __launch_bounds__(256) void memout_kernel(const float* __restrict__ sq,
                                                     const float* __restrict__ memories,
                                                     const float* __restrict__ rel,
                                                     const float* __restrict__ weights,
                                                     const float* __restrict__ gate,
                                                     float* __restrict__ combined) {
    const int h = blockIdx.x;
    const int sbase = blockIdx.y * 64;
    __shared__ float mem_s[NMEM][64][64];
    __shared__ float sqrow[4][64];
    const int tid = threadIdx.x;
#pragma unroll
    for (int m = 0; m < NMEM; ++m) {
        const float* src = memories + (size_t)(m * NHEAD + h) * HD * HD;
        float* dst = &mem_s[m][0][0];
#pragma unroll
        for (int j = 0; j < 4; ++j)
            *(float4*)(dst + j * 1024 + tid * 4) = *(const float4*)(src + j * 1024 + tid * 4);
    }
    float w_h[NMEM];
#pragma unroll
    for (int m = 0; m < NMEM; ++m) w_h[m] = weights[m * NHEAD + h];
    const float g = 1.f / (1.f + __expf(-gate[h]));
    const int e = tid & 63;
    const int sl = tid >> 6;
    for (int s0 = 0; s0 < 64; s0 += 4) {
        const int s = sbase + s0 + sl;
        __syncthreads();
        sqrow[sl][e] = sq[(size_t)s * H_DIM + h * HD + e];
        __syncthreads();
        float acc = 0.f;
#pragma unroll
        for (int m = 0; m < NMEM; ++m) {
            const float r = rel[(size_t)(m * NHEAD + h) * S_LEN + s];
            const float cm = w_h[m] / fmaxf(r, EPS_C);
            float part = 0.f;
#pragma unroll
            for (int d = 0; d < 64; ++d)
                part = fmaf(sqrow[sl][d], mem_s[m][d][e], part);
            acc = fmaf(cm, part, acc);
        }
        combined[(size_t)s * H_DIM + h * HD + e] = g * acc;
    }
}

// ---------------------------------------------------------------------------
// Per-chunk KV state
// ---------------------------------------------------------------------------
__global__ __launch_bounds__(256) void chunkkv_kernel(const float* __restrict__ sk,
                                                      const float* __restrict__ v,
                                                      float* __restrict__ ckv,
                                                      float* __restrict__ cks) {
    const int h = blockIdx.x;
    const int c = blockIdx.y;
    const int s0 = c * CLEN;
    __shared__ float sks[64][64];
    __shared__ float vs[64][64];
    const int tid = threadIdx.x;
#pragma unroll
    for (int j = 0; j < 4; ++j) {
        const int idx = j * 1024 + tid * 4;
        const int r = idx >> 6, cc = idx & 63;
        *(float4*)&sks[r][cc] = *(const float4*)&sk[(size_t)(s0 + r) * H_DIM + h * HD + cc];
        *(float4*)&vs[r][cc]  = *(const float4*)&v[(size_t)(s0 + r) * H_DIM + h * HD + cc];
    }
    __syncthreads();
    const int e = tid & 63;
    const int db = (tid >> 6) * 16;
    float acc[16] = {};
    for (int s = 0; s < 64; ++s) {
        const float vv = vs[s][e];
#pragma unroll
        for (int i = 0; i < 16; ++i) acc[i] = fmaf(sks[s][db + i], vv, acc[i]);
    }
    float* outp = ckv + (size_t)(h * NCHUNK + c) * HD * HD;
#pragma unroll
    for (int i = 0; i < 16; ++i) outp[(db + i) * 64 + e] = acc[i];
    if (tid < 64) {
        float ks = 0.f;
        for (int s = 0; s < 64; ++s) ks += sks[s][tid];
        cks[(size_t)(h * NCHUNK + c) * HD + tid] = ks;
    }
}

// ---------------------------------------------------------------------------
// In-place exclusive prefix over chunks (per head)
// ---------------------------------------------------------------------------
__global__ __launch_bounds__(256) void prefix_kernel(float* __restrict__ ckv,
                                                     float* __restrict__ cks) {
    const int h = blockIdx.x;
    const int tid = threadIdx.x;
    const int base = tid * 16;
    float run[16];
#pragma unroll
    for (int i = 0; i < 16; ++i) run[i] = 0.f;
    for (int c = 0; c < NCHUNK; ++c) {
        float* p = ckv + (size_t)(h * NCHUNK + c) * 4096 + base;
#pragma unroll
        for (int i = 0; i < 16; ++i) {
            const float cur = p[i];
            p[i] = run[i];
            run[i] += cur;
        }
    }
    if (tid < 64) {
        float rk = 0.f;
        for (int c = 0; c < NCHUNK; ++c) {
            float* p = cks + (size_t)(h * NCHUNK + c) * HD + tid;
            const float cur = *p;
            *p = rk;
            rk += cur;
        }
    }
}

// ---------------------------------------------------------------------------
// Causal linear attention output for one (head, chunk)
// ---------------------------------------------------------------------------
__global__ __launch_bounds__(256) void attnout_kernel(const float* __restrict__ sq,
                                                      const float* __restrict__ sk,
                                                      const float* __restrict__ v,
                                                      const float* __restrict__ ckv,
                                                      const float* __restrict__ cks,
                                                      const float* __restrict__ gate,
                                                      float* __restrict__ combined) {
    const int h = blockIdx.x;
    const int c = blockIdx.y;
    const int s0 = c * CLEN;
    __shared__ float sqs[64][64], sks[64][64], vs[64][64], kvp[64][64], Am[64][64];
    __shared__ float kp[64], den[64];
    const int tid = threadIdx.x;
    const float* kvsrc = ckv + (size_t)(h * NCHUNK + c) * 4096;
#pragma unroll
    for (int j = 0; j < 4; ++j) {
        const int idx = j * 1024 + tid * 4;
        const int r = idx >> 6, cc = idx & 63;
        *(float4*)&sqs[r][cc] = *(const float4*)&sq[(size_t)(s0 + r) * H_DIM + h * HD + cc];
        *(float4*)&sks[r][cc] = *(const float4*)&sk[(size_t)(s0 + r) * H_DIM + h * HD + cc];
        *(float4*)&vs[r][cc]  = *(const float4*)&v[(size_t)(s0 + r) * H_DIM + h * HD + cc];
        *(float4*)(&kvp[0][0] + idx) = *(const float4*)(kvsrc + idx);
    }
    if (tid < 64) kp[tid] = cks[(size_t)(h * NCHUNK + c) * HD + tid];
    __syncthreads();

    const int s_a = tid >> 2;
    const int tb = (tid & 3) * 16;
#pragma unroll
    for (int i = 0; i < 16; ++i) {
        const int t = tb + i;
        float dot = 0.f;
        if (t <= s_a) {
#pragma unroll
            for (int d = 0; d < 64; ++d)
                dot = fmaf(sqs[s_a][d], sks[t][d], dot);
        }
        Am[s_a][t] = dot;
    }
    __syncthreads();
    if (tid < 64) {
        float rs = 0.f;
        for (int t = 0; t <= tid; ++t) rs += Am[tid][t];
        float dq = 0.f;
#pragma unroll
        for (int d = 0; d < 64; ++d) dq = fmaf(sqs[tid][d], kp[d], dq);
        den[tid] = fmaxf(dq + rs, EPS_C);
    }
    __syncthreads();

    const int e = tid & 63;
    const int sb = (tid >> 6) * 16;
    const float g = 1.f / (1.f + __expf(-gate[h]));
    const float gl = 1.f - g;
#pragma unroll
    for (int i = 0; i < 16; ++i) {
        const int s = sb + i;
        float num = 0.f;
#pragma unroll
        for (int d = 0; d < 64; ++d)
            num = fmaf(sqs[s][d], kvp[d][e], num);
        for (int t = 0; t <= s; ++t)
            num = fmaf(Am[s][t], vs[t][e], num);
        const size_t oidx = (size_t)(s0 + s) * H_DIM + h * HD + e;
        combined[oidx] += gl * num / den[s];
    }
}

extern "C" void kernel_launch(void* const* d_in, const int* in_sizes, int n_in,
                              void* d_out, int out_size, void* d_ws, size_t ws_size,
                              hipStream_t stream) {
    const float* hidden   = (const float*)d_in[0];
    const float* w_q      = (const float*)d_in[1];
    const float* w_k      = (const float*)d_in[2];
    const float* w_v      = (const float*)d_in[3];
    const float* w_o      = (const float*)d_in[4];
    const float* gate     = (const float*)d_in[5];
    const float* memories = (const float*)d_in[6];
    const float* memnorms = (const float*)d_in[7];
    float* out = (float*)d_out;

    float* ws = (float*)d_ws;
    size_t off = 0;
    float* sq       = ws + off; off += (size_t)S_LEN * H_DIM;
    float* sk       = ws + off; off += (size_t)S_LEN * H_DIM;
    float* vv       = ws + off; off += (size_t)S_LEN * H_DIM;
    float* combined = ws + off; off += (size_t)S_LEN * H_DIM;
    float* rel      = ws + off; off += (size_t)NMEM * NHEAD * S_LEN;
    float* relsum   = ws + off; off += NMEM * NHEAD;
    float* weights  = ws + off; off += 64;  // padded for alignment
    float* ckv      = ws + off; off += (size_t)NHEAD * NCHUNK * HD * HD;
    float* cks      = ws + off; off += (size_t)NHEAD * NCHUNK * HD;
    // bf16 scratch (ushort), 16B-aligned
    unsigned short* hb  = (unsigned short*)(ws + off); off += (size_t)S_LEN * H_DIM / 2;  // also reused for combined bf16
    unsigned short* wb  = (unsigned short*)(ws + off); off += (size_t)3 * H_DIM * H_DIM / 2;
    unsigned short* wob = (unsigned short*)(ws + off); off += (size_t)H_DIM * H_DIM / 2;

    // --- conversions ---
    cvt_bf16_kernel<<<S_LEN * H_DIM / 2048, 256, 0, stream>>>(hidden, hb);
    cvt_bf16_kernel<<<H_DIM * H_DIM / 2048, 256, 0, stream>>>(w_q, wb);
    cvt_bf16_kernel<<<H_DIM * H_DIM / 2048, 256, 0, stream>>>(w_k, wb + (size_t)H_DIM * H_DIM);
    cvt_bf16_kernel<<<H_DIM * H_DIM / 2048, 256, 0, stream>>>(w_v, wb + (size_t)2 * H_DIM * H_DIM);
    cvt_bf16_kernel<<<H_DIM * H_DIM / 2048, 256, 0, stream>>>(w_o, wob);

    // --- fused QKV projection (bf16 MFMA) ---
    gemm_mfma_kernel<1><<<dim3(S_LEN / 128, 3 * H_DIM / 128), 256, 0, stream>>>(
        hb, wb, sq, sk, vv, H_DIM);

    // --- memory retrieval + causal linear attention (f32) ---
    rel_kernel<<<NMEM * NHEAD, 256, 0, stream>>>(sq, memnorms, rel, relsum);
    weights_kernel<<<1, 64, 0, stream>>>(relsum, weights);
    memout_kernel<<<dim3(NHEAD, S_LEN / 64), 256, 0, stream>>>(sq, memories, rel, weights, gate, combined);
    chunkkv_kernel<<<dim3(NHEAD, NCHUNK), 256, 0, stream>>>(sk, vv, ckv, cks);
    prefix_kernel<<<NHEAD, 256, 0, stream>>>(ckv, cks);
    attnout_kernel<<<dim3(NHEAD, NCHUNK), 256, 0, stream>>>(sq, sk, vv, ckv, cks, gate, combined);

    // --- output projection ---
    cvt_bf16_kernel<<<S_LEN * H_DIM / 2048, 256, 0, stream>>>(combined, hb);
    gemm_mfma_kernel<0><<<dim3(S_LEN / 128, H_DIM / 128), 256, 0, stream>>>(
        hb, wob, out, out, out, H_DIM);
}

// Round 3
// 169.355 us; speedup vs baseline: 2.5910x; 1.4782x over previous
//
#include <hip/hip_runtime.h>
#include <hip/hip_bf16.h>
#include <math.h>

#define S_LEN 2048
#define H_DIM 1024
#define NHEAD 16
#define HD 64
#define NMEM 4
#define NCHUNK 32
#define CLEN 64
#define EPS_C 1e-6f

typedef __attribute__((ext_vector_type(8))) short bf16x8;
typedef __attribute__((ext_vector_type(4))) float f32x4;
typedef __attribute__((ext_vector_type(8))) unsigned short u16x8;

__device__ __forceinline__ unsigned short f2bf(float f) {
    unsigned int u = __float_as_uint(f);
    u += 0x7FFFu + ((u >> 16) & 1u);   // round-to-nearest-even
    return (unsigned short)(u >> 16);
}
__device__ __forceinline__ float bf2f(unsigned short u) {
    return __uint_as_float((unsigned int)u << 16);
}

// ---------------------------------------------------------------------------
// f32 -> bf16 conversion, 8 elems/thread
// ---------------------------------------------------------------------------
__global__ __launch_bounds__(256) void cvt_bf16_kernel(const float* __restrict__ in,
                                                       unsigned short* __restrict__ out) {
    const int i = (blockIdx.x * 256 + threadIdx.x) * 8;
    float4 a = *(const float4*)(in + i);
    float4 b = *(const float4*)(in + i + 4);
    u16x8 o;
    o[0] = f2bf(a.x); o[1] = f2bf(a.y); o[2] = f2bf(a.z); o[3] = f2bf(a.w);
    o[4] = f2bf(b.x); o[5] = f2bf(b.y); o[6] = f2bf(b.z); o[7] = f2bf(b.w);
    *(u16x8*)(out + i) = o;
}

// ---------------------------------------------------------------------------
// MFMA bf16 GEMM (m97 structure): C[m,n] = sum_k A[m,k]*B[n,k]
// MODE 0: f32 out only (no act).
// MODE 1: qkv fused — seg0: elu1 -> f32out + b0; seg1: elu1 -> b1; seg2: none -> b2.
// ---------------------------------------------------------------------------
template <int MODE>
__global__ __launch_bounds__(256) void gemm_mfma_kernel(const unsigned short* __restrict__ A,
                                                        const unsigned short* __restrict__ B,
                                                        float* __restrict__ f32out,
                                                        unsigned short* __restrict__ b0,
                                                        unsigned short* __restrict__ b1,
                                                        unsigned short* __restrict__ b2,
                                                        int K) {
    __shared__ unsigned short Als[128][32];
    __shared__ unsigned short Bls[128][32];
    const int tid  = threadIdx.x;
    const int lane = tid & 63;
    const int wv   = tid >> 6;
    const int wr   = wv >> 1;
    const int wc   = wv & 1;
    const int bm   = blockIdx.x * 128;
    const int bn   = blockIdx.y * 128;

    const int srow = (wv << 5) + (lane >> 2);
    const int skc  = (lane & 3) << 3;
    const unsigned short* gA = A + (size_t)(bm + srow) * K + skc;
    const unsigned short* gB = B + (size_t)(bn + srow) * K + skc;

    const int frow = lane & 15;
    const int fkof = (lane >> 4) << 3;

    f32x4 acc[4][4] = {};

    for (int k0 = 0; k0 < K; k0 += 32) {
        __syncthreads();
        __builtin_amdgcn_global_load_lds(
            (const __attribute__((address_space(1))) void*)(gA + k0),
            (__attribute__((address_space(3))) void*)&Als[(wv << 5)][0], 16, 0, 0);
        __builtin_amdgcn_global_load_lds(
            (const __attribute__((address_space(1))) void*)(gA + k0 + 16 * (size_t)K),
            (__attribute__((address_space(3))) void*)&Als[(wv << 5) + 16][0], 16, 0, 0);
        __builtin_amdgcn_global_load_lds(
            (const __attribute__((address_space(1))) void*)(gB + k0),
            (__attribute__((address_space(3))) void*)&Bls[(wv << 5)][0], 16, 0, 0);
        __builtin_amdgcn_global_load_lds(
            (const __attribute__((address_space(1))) void*)(gB + k0 + 16 * (size_t)K),
            (__attribute__((address_space(3))) void*)&Bls[(wv << 5) + 16][0], 16, 0, 0);
        __syncthreads();

        bf16x8 af[4], bf[4];
#pragma unroll
        for (int mi = 0; mi < 4; ++mi)
            af[mi] = *(const bf16x8*)&Als[wr * 64 + mi * 16 + frow][fkof];
#pragma unroll
        for (int ni = 0; ni < 4; ++ni)
            bf[ni] = *(const bf16x8*)&Bls[wc * 64 + ni * 16 + frow][fkof];
#pragma unroll
        for (int mi = 0; mi < 4; ++mi)
#pragma unroll
            for (int ni = 0; ni < 4; ++ni)
                acc[mi][ni] = __builtin_amdgcn_mfma_f32_16x16x32_bf16(af[mi], bf[ni], acc[mi][ni], 0, 0, 0);
    }

    float* fdst = f32out;
    unsigned short* bdst = b0;
    int colbase = bn;
    bool act = false;
    if (MODE == 1) {
        const int seg = bn >> 10;
        bdst = (seg == 0) ? b0 : ((seg == 1) ? b1 : b2);
        fdst = (seg == 0) ? f32out : nullptr;
        colbase = bn & 1023;
        act = (seg < 2);
    }
    const int crow = (lane >> 4) << 2;
    const int ccol = lane & 15;
#pragma unroll
    for (int mi = 0; mi < 4; ++mi) {
#pragma unroll
        for (int ni = 0; ni < 4; ++ni) {
            const int col = colbase + wc * 64 + ni * 16 + ccol;
#pragma unroll
            for (int r = 0; r < 4; ++r) {
                const int row = bm + wr * 64 + mi * 16 + crow + r;
                float x = acc[mi][ni][r];
                if (MODE == 1 && act) x = (x > 0.f) ? (x + 1.f) : __expf(x);
                if (MODE == 0) {
                    fdst[(size_t)row * 1024 + col] = x;
                } else {
                    if (fdst) fdst[(size_t)row * 1024 + col] = x;
                    bdst[(size_t)row * 1024 + col] = f2bf(x);
                }
            }
        }
    }
}

// ---------------------------------------------------------------------------
// rel[m,h,s] = sum_d sq[s, h*64+d] * norms[m,h,d];  relsum[m,h] = sum_s rel
// ---------------------------------------------------------------------------
__global__ __launch_bounds__(256) void rel_kernel(const float* __restrict__ sq,
                                                  const float* __restrict__ norms,
                                                  float* __restrict__ rel,
                                                  float* __restrict__ relsum) {
    const int m = blockIdx.x >> 4;
    const int h = blockIdx.x & 15;
    __shared__ float nl[64];
    __shared__ float red[256];
    const int tid = threadIdx.x;
    if (tid < 64) nl[tid] = norms[(size_t)(m * NHEAD + h) * HD + tid];
    __syncthreads();
    float lsum = 0.f;
    for (int s = tid; s < S_LEN; s += 256) {
        const float* row = sq + (size_t)s * H_DIM + h * HD;
        float dot = 0.f;
#pragma unroll
        for (int d = 0; d < 64; d += 4) {
            float4 v = *(const float4*)(row + d);
            dot += v.x * nl[d] + v.y * nl[d + 1] + v.z * nl[d + 2] + v.w * nl[d + 3];
        }
        rel[(size_t)(m * NHEAD + h) * S_LEN + s] = dot;
        lsum += dot;
    }
    red[tid] = lsum;
    __syncthreads();
    for (int o = 128; o > 0; o >>= 1) {
        if (tid < o) red[tid] += red[tid + o];
        __syncthreads();
    }
    if (tid == 0) relsum[m * NHEAD + h] = red[0];
}

__global__ void weights_kernel(const float* __restrict__ relsum,
                               float* __restrict__ weights) {
    const int h = threadIdx.x;
    if (h >= NHEAD) return;
    float v[NMEM];
    float mx = -1e30f;
#pragma unroll
    for (int m = 0; m < NMEM; ++m) {
        v[m] = relsum[m * NHEAD + h] / (float)S_LEN;
        mx = fmaxf(mx, v[m]);
    }
    float sum = 0.f;
#pragma unroll
    for (int m = 0; m < NMEM; ++m) { v[m] = __expf(v[m] - mx); sum += v[m]; }
#pragma unroll
    for (int m = 0; m < NMEM; ++m) weights[m * NHEAD + h] = v[m] / sum;
}

// ---------------------------------------------------------------------------
// memout: combined[s, h*64+e] = g * sum_m (w[m,h]/max(rel,EPS)) * (sq[s]·mem[m,:,e])
// ---------------------------------------------------------------------------
__global__ __launch_bounds__(256) void memout_kernel(const float* __restrict__ sq,
                                                     const float* __restrict__ memories,
                                                     const float* __restrict__ rel,
                                                     const float* __restrict__ weights,
                                                     const float* __restrict__ gate,
                                                     float* __restrict__ combined) {
    const int h = blockIdx.x;
    const int sbase = blockIdx.y * 64;
    __shared__ float mem_s[NMEM][64][64];
    __shared__ float sqrow[4][64];
    const int tid = threadIdx.x;
#pragma unroll
    for (int m = 0; m < NMEM; ++m) {
        const float* src = memories + (size_t)(m * NHEAD + h) * HD * HD;
        float* dst = &mem_s[m][0][0];
#pragma unroll
        for (int j = 0; j < 4; ++j)
            *(float4*)(dst + j * 1024 + tid * 4) = *(const float4*)(src + j * 1024 + tid * 4);
    }
    float w_h[NMEM];
#pragma unroll
    for (int m = 0; m < NMEM; ++m) w_h[m] = weights[m * NHEAD + h];
    const float g = 1.f / (1.f + __expf(-gate[h]));
    const int e = tid & 63;
    const int sl = tid >> 6;
    for (int s0 = 0; s0 < 64; s0 += 4) {
        const int s = sbase + s0 + sl;
        __syncthreads();
        sqrow[sl][e] = sq[(size_t)s * H_DIM + h * HD + e];
        __syncthreads();
        float acc = 0.f;
#pragma unroll
        for (int m = 0; m < NMEM; ++m) {
            const float r = rel[(size_t)(m * NHEAD + h) * S_LEN + s];
            const float cm = w_h[m] / fmaxf(r, EPS_C);
            float part = 0.f;
#pragma unroll
            for (int d = 0; d < 64; ++d)
                part = fmaf(sqrow[sl][d], mem_s[m][d][e], part);
            acc = fmaf(cm, part, acc);
        }
        combined[(size_t)s * H_DIM + h * HD + e] = g * acc;
    }
}

// ---------------------------------------------------------------------------
// Per-chunk KV state (bf16 inputs, f32 accumulate)
// ---------------------------------------------------------------------------
__global__ __launch_bounds__(256) void chunkkv_kernel(const unsigned short* __restrict__ kb,
                                                      const unsigned short* __restrict__ vb,
                                                      float* __restrict__ ckv,
                                                      float* __restrict__ cks) {
    const int h = blockIdx.x;
    const int c = blockIdx.y;
    const int s0 = c * CLEN;
    __shared__ float sks[64][64];
    __shared__ float vs[64][64];
    const int tid = threadIdx.x;
#pragma unroll
    for (int j = 0; j < 2; ++j) {
        const int idx = j * 2048 + tid * 8;
        const int r = idx >> 6, cc = idx & 63;
        u16x8 k8 = *(const u16x8*)&kb[(size_t)(s0 + r) * H_DIM + h * HD + cc];
        u16x8 v8 = *(const u16x8*)&vb[(size_t)(s0 + r) * H_DIM + h * HD + cc];
#pragma unroll
        for (int i = 0; i < 8; ++i) {
            sks[r][cc + i] = bf2f(k8[i]);
            vs[r][cc + i]  = bf2f(v8[i]);
        }
    }
    __syncthreads();
    const int e = tid & 63;
    const int db = (tid >> 6) * 16;
    float acc[16] = {};
    for (int s = 0; s < 64; ++s) {
        const float vv = vs[s][e];
#pragma unroll
        for (int i = 0; i < 16; ++i) acc[i] = fmaf(sks[s][db + i], vv, acc[i]);
    }
    float* outp = ckv + (size_t)(h * NCHUNK + c) * HD * HD;
#pragma unroll
    for (int i = 0; i < 16; ++i) outp[(db + i) * 64 + e] = acc[i];
    if (tid < 64) {
        float ks = 0.f;
        for (int s = 0; s < 64; ++s) ks += sks[s][tid];
        cks[(size_t)(h * NCHUNK + c) * HD + tid] = ks;
    }
}

// ---------------------------------------------------------------------------
// Exclusive prefix over chunks. grid (NHEAD, 4), 256 threads, 4 chains/thread
// ---------------------------------------------------------------------------
__global__ __launch_bounds__(256) void prefix_kernel(float* __restrict__ ckv,
                                                     float* __restrict__ cks) {
    const int h = blockIdx.x;
    const int g = blockIdx.y;
    const int tid = threadIdx.x;
    const int e = tid & 63;
    const int d0 = g * 16 + (tid >> 6) * 4;
    float run[4] = {0.f, 0.f, 0.f, 0.f};
    for (int c = 0; c < NCHUNK; ++c) {
        float* base = ckv + (size_t)(h * NCHUNK + c) * 4096;
#pragma unroll
        for (int i = 0; i < 4; ++i) {
            float* p = base + (d0 + i) * 64 + e;
            const float cur = *p;
            *p = run[i];
            run[i] += cur;
        }
    }
    if (g == 0 && tid < 64) {
        float rk = 0.f;
        for (int c = 0; c < NCHUNK; ++c) {
            float* p = cks + (size_t)(h * NCHUNK + c) * HD + tid;
            const float cur = *p;
            *p = rk;
            rk += cur;
        }
    }
}

// ---------------------------------------------------------------------------
// MFMA causal linear attention for one (head, chunk).
// LDS: Q,K row-major [r][k]; V,KV transposed [e][k]; all bf16 XOR-swizzled.
// combined += (1-g)*num/den  (RMW), also emits bf16 copy for the final GEMM.
// ---------------------------------------------------------------------------
__global__ __launch_bounds__(256) void attnout_mfma_kernel(const unsigned short* __restrict__ qb,
                                                           const unsigned short* __restrict__ kb,
                                                           const unsigned short* __restrict__ vb,
                                                           const float* __restrict__ ckv,
                                                           const float* __restrict__ cks,
                                                           const float* __restrict__ gate,
                                                           float* __restrict__ combined,
                                                           unsigned short* __restrict__ cb) {
    const int h = blockIdx.x;
    const int c = blockIdx.y;
    const int s0 = c * CLEN;
    __shared__ unsigned short Qs[4096], Ks[4096], VsT[4096], KVsT[4096], Ps[4096];
    __shared__ float kp_lds[64];
    __shared__ float den_lds[64];
    char* Qb  = (char*)Qs;
    char* Kb  = (char*)Ks;
    char* Vb  = (char*)VsT;
    char* KVb = (char*)KVsT;
    char* Pb  = (char*)Ps;
    const int tid = threadIdx.x;
    const int lane = tid & 63;
    const int w = tid >> 6;

#define SWZ(row, colbyte) ((row) * 128 + ((colbyte) ^ (((row) & 7) << 4)))

    // --- stage Q, K (row-major), V (transposed) ---
#pragma unroll
    for (int p = 0; p < 2; ++p) {
        const int idx = p * 2048 + tid * 8;
        const int r = idx >> 6, cc = idx & 63;
        const size_t gidx = (size_t)(s0 + r) * H_DIM + h * HD + cc;
        u16x8 q8 = *(const u16x8*)&qb[gidx];
        u16x8 k8 = *(const u16x8*)&kb[gidx];
        u16x8 v8 = *(const u16x8*)&vb[gidx];
        *(u16x8*)(Qb + SWZ(r, cc * 2)) = q8;
        *(u16x8*)(Kb + SWZ(r, cc * 2)) = k8;
#pragma unroll
        for (int j = 0; j < 8; ++j)
            *(unsigned short*)(Vb + SWZ(cc + j, r * 2)) = (unsigned short)v8[j];
    }
    // --- stage KV^T (f32 -> bf16, transposed) ---
    const float* kvsrc = ckv + (size_t)(h * NCHUNK + c) * 4096;
#pragma unroll
    for (int p = 0; p < 4; ++p) {
        const int idx = p * 1024 + tid * 4;
        const int d = idx >> 6, e = idx & 63;
        float4 f = *(const float4*)&kvsrc[idx];
        *(unsigned short*)(KVb + SWZ(e + 0, d * 2)) = f2bf(f.x);
        *(unsigned short*)(KVb + SWZ(e + 1, d * 2)) = f2bf(f.y);
        *(unsigned short*)(KVb + SWZ(e + 2, d * 2)) = f2bf(f.z);
        *(unsigned short*)(KVb + SWZ(e + 3, d * 2)) = f2bf(f.w);
    }
    if (tid < 64) kp_lds[tid] = cks[(size_t)(h * NCHUNK + c) * HD + tid];
    __syncthreads();

    // --- den_init[s] = sq[s]·kpre ---
    {
        const int s = tid >> 2, part = tid & 3;
        float acc = 0.f;
#pragma unroll
        for (int j = 0; j < 16; ++j) {
            const int d = part * 16 + j;
            acc += bf2f(*(unsigned short*)(Qb + SWZ(s, d * 2))) * kp_lds[d];
        }
        acc += __shfl_xor(acc, 1);
        acc += __shfl_xor(acc, 2);
        if (part == 0) den_lds[s] = acc;
    }

    // --- QK^T ---
    const int sb = w * 16;
    const int fr = lane & 15;
    const int fk = (lane >> 4) * 8;
    f32x4 aqk[4] = {};
#pragma unroll
    for (int kk = 0; kk < 2; ++kk) {
        const int kel = kk * 32 + fk;
        bf16x8 afq = *(bf16x8*)(Qb + SWZ(sb + fr, kel * 2));
#pragma unroll
        for (int nt = 0; nt < 4; ++nt) {
            bf16x8 bfk = *(bf16x8*)(Kb + SWZ(nt * 16 + fr, kel * 2));
            aqk[nt] = __builtin_amdgcn_mfma_f32_16x16x32_bf16(afq, bfk, aqk[nt], 0, 0, 0);
        }
    }
    // mask (t<=s), write P bf16, accumulate row sums
    float rs[4] = {0.f, 0.f, 0.f, 0.f};
    const int srow0 = sb + (lane >> 4) * 4;
#pragma unroll
    for (int nt = 0; nt < 4; ++nt) {
        const int t = nt * 16 + fr;
#pragma unroll
        for (int r = 0; r < 4; ++r) {
            const int s = srow0 + r;
            const float pv = (t <= s) ? aqk[nt][r] : 0.f;
            rs[r] += pv;
            *(unsigned short*)(Pb + SWZ(s, t * 2)) = f2bf(pv);
        }
    }
#pragma unroll
    for (int m = 1; m < 16; m <<= 1) {
        rs[0] += __shfl_xor(rs[0], m);
        rs[1] += __shfl_xor(rs[1], m);
        rs[2] += __shfl_xor(rs[2], m);
        rs[3] += __shfl_xor(rs[3], m);
    }
    if (fr == 0) {
#pragma unroll
        for (int r = 0; r < 4; ++r) den_lds[srow0 + r] += rs[r];
    }
    __syncthreads();

    // --- num = P@V + Q@KVpre; epilogue ---
    const float g = 1.f / (1.f + __expf(-gate[h]));
    const float gl = 1.f - g;
#pragma unroll
    for (int nt = 0; nt < 4; ++nt) {
        f32x4 acc = {};
#pragma unroll
        for (int kk = 0; kk < 2; ++kk) {
            const int kel = kk * 32 + fk;
            bf16x8 ap  = *(bf16x8*)(Pb + SWZ(sb + fr, kel * 2));
            bf16x8 bv  = *(bf16x8*)(Vb + SWZ(nt * 16 + fr, kel * 2));
            acc = __builtin_amdgcn_mfma_f32_16x16x32_bf16(ap, bv, acc, 0, 0, 0);
            bf16x8 aq  = *(bf16x8*)(Qb + SWZ(sb + fr, kel * 2));
            bf16x8 bkv = *(bf16x8*)(KVb + SWZ(nt * 16 + fr, kel * 2));
            acc = __builtin_amdgcn_mfma_f32_16x16x32_bf16(aq, bkv, acc, 0, 0, 0);
        }
        const int e = nt * 16 + fr;
#pragma unroll
        for (int r = 0; r < 4; ++r) {
            const int s = srow0 + r;
            const float den = fmaxf(den_lds[s], EPS_C);
            const size_t oidx = (size_t)(s0 + s) * H_DIM + h * HD + e;
            const float val = combined[oidx] + gl * acc[r] / den;
            combined[oidx] = val;
            cb[oidx] = f2bf(val);
        }
    }
#undef SWZ
}

extern "C" void kernel_launch(void* const* d_in, const int* in_sizes, int n_in,
                              void* d_out, int out_size, void* d_ws, size_t ws_size,
                              hipStream_t stream) {
    const float* hidden   = (const float*)d_in[0];
    const float* w_q      = (const float*)d_in[1];
    const float* w_k      = (const float*)d_in[2];
    const float* w_v      = (const float*)d_in[3];
    const float* w_o      = (const float*)d_in[4];
    const float* gate     = (const float*)d_in[5];
    const float* memories = (const float*)d_in[6];
    const float* memnorms = (const float*)d_in[7];
    float* out = (float*)d_out;

    float* ws = (float*)d_ws;
    size_t off = 0;
    float* sq       = ws + off; off += (size_t)S_LEN * H_DIM;
    float* combined = ws + off; off += (size_t)S_LEN * H_DIM;
    float* rel      = ws + off; off += (size_t)NMEM * NHEAD * S_LEN;
    float* relsum   = ws + off; off += NMEM * NHEAD;
    float* weights  = ws + off; off += 64;
    float* ckv      = ws + off; off += (size_t)NHEAD * NCHUNK * HD * HD;
    float* cks      = ws + off; off += (size_t)NHEAD * NCHUNK * HD;
    unsigned short* hb  = (unsigned short*)(ws + off); off += (size_t)S_LEN * H_DIM / 2;
    unsigned short* wb  = (unsigned short*)(ws + off); off += (size_t)3 * H_DIM * H_DIM / 2;
    unsigned short* wob = (unsigned short*)(ws + off); off += (size_t)H_DIM * H_DIM / 2;
    unsigned short* qb  = (unsigned short*)(ws + off); off += (size_t)S_LEN * H_DIM / 2;
    unsigned short* kb  = (unsigned short*)(ws + off); off += (size_t)S_LEN * H_DIM / 2;
    unsigned short* vb  = (unsigned short*)(ws + off); off += (size_t)S_LEN * H_DIM / 2;
    unsigned short* cb  = (unsigned short*)(ws + off); off += (size_t)S_LEN * H_DIM / 2;

    // --- input conversions ---
    cvt_bf16_kernel<<<S_LEN * H_DIM / 2048, 256, 0, stream>>>(hidden, hb);
    cvt_bf16_kernel<<<H_DIM * H_DIM / 2048, 256, 0, stream>>>(w_q, wb);
    cvt_bf16_kernel<<<H_DIM * H_DIM / 2048, 256, 0, stream>>>(w_k, wb + (size_t)H_DIM * H_DIM);
    cvt_bf16_kernel<<<H_DIM * H_DIM / 2048, 256, 0, stream>>>(w_v, wb + (size_t)2 * H_DIM * H_DIM);
    cvt_bf16_kernel<<<H_DIM * H_DIM / 2048, 256, 0, stream>>>(w_o, wob);

    // --- fused QKV projection: sq f32 + q/k/v bf16 ---
    gemm_mfma_kernel<1><<<dim3(S_LEN / 128, 3 * H_DIM / 128), 256, 0, stream>>>(
        hb, wb, sq, qb, kb, vb, H_DIM);

    // --- memory retrieval path ---
    rel_kernel<<<NMEM * NHEAD, 256, 0, stream>>>(sq, memnorms, rel, relsum);
    weights_kernel<<<1, 64, 0, stream>>>(relsum, weights);
    memout_kernel<<<dim3(NHEAD, S_LEN / 64), 256, 0, stream>>>(sq, memories, rel, weights, gate, combined);

    // --- causal linear attention ---
    chunkkv_kernel<<<dim3(NHEAD, NCHUNK), 256, 0, stream>>>(kb, vb, ckv, cks);
    prefix_kernel<<<dim3(NHEAD, 4), 256, 0, stream>>>(ckv, cks);
    attnout_mfma_kernel<<<dim3(NHEAD, NCHUNK), 256, 0, stream>>>(qb, kb, vb, ckv, cks, gate, combined, cb);

    // --- output projection ---
    gemm_mfma_kernel<0><<<dim3(S_LEN / 128, H_DIM / 128), 256, 0, stream>>>(
        cb, wob, out, nullptr, nullptr, nullptr, H_DIM);
}

// Round 4
// 120.103 us; speedup vs baseline: 3.6535x; 1.4101x over previous
//
#include <hip/hip_runtime.h>
#include <hip/hip_bf16.h>
#include <math.h>

#define S_LEN 2048
#define H_DIM 1024
#define NHEAD 16
#define HD 64
#define NMEM 4
#define NCHUNK 32
#define CLEN 64
#define EPS_C 1e-6f

typedef __attribute__((ext_vector_type(8))) short bf16x8;
typedef __attribute__((ext_vector_type(4))) float f32x4;
typedef __attribute__((ext_vector_type(8))) unsigned short u16x8;
typedef __attribute__((ext_vector_type(4))) unsigned short u16x4;

__device__ __forceinline__ unsigned short f2bf(float f) {
    unsigned int u = __float_as_uint(f);
    u += 0x7FFFu + ((u >> 16) & 1u);   // round-to-nearest-even
    return (unsigned short)(u >> 16);
}
__device__ __forceinline__ float bf2f(unsigned short u) {
    return __uint_as_float((unsigned int)u << 16);
}

// ---------------------------------------------------------------------------
// f32 -> bf16 conversion, 8 elems/thread
// ---------------------------------------------------------------------------
__global__ __launch_bounds__(256) void cvt_bf16_kernel(const float* __restrict__ in,
                                                       unsigned short* __restrict__ out) {
    const int i = (blockIdx.x * 256 + threadIdx.x) * 8;
    float4 a = *(const float4*)(in + i);
    float4 b = *(const float4*)(in + i + 4);
    u16x8 o;
    o[0] = f2bf(a.x); o[1] = f2bf(a.y); o[2] = f2bf(a.z); o[3] = f2bf(a.w);
    o[4] = f2bf(b.x); o[5] = f2bf(b.y); o[6] = f2bf(b.z); o[7] = f2bf(b.w);
    *(u16x8*)(out + i) = o;
}

// ---------------------------------------------------------------------------
// memories [m,h,d,e] f32 -> mbT [m,h,e,d] bf16 (one 64x64 tile per block)
// ---------------------------------------------------------------------------
__global__ __launch_bounds__(256) void memT_kernel(const float* __restrict__ mem,
                                                   unsigned short* __restrict__ mbT) {
    const int mh = blockIdx.x;
    __shared__ float t[64][65];
    const float* src = mem + (size_t)mh * 4096;
    const int tid = threadIdx.x;
#pragma unroll
    for (int j = 0; j < 4; ++j) {
        const int idx = j * 1024 + tid * 4;
        *(float4*)&t[idx >> 6][idx & 63] = *(const float4*)&src[idx];
    }
    __syncthreads();
    unsigned short* dst = mbT + (size_t)mh * 4096;
#pragma unroll
    for (int j = 0; j < 4; ++j) {
        const int idx = j * 1024 + tid * 4;
        const int e = idx >> 6, d = idx & 63;
        u16x4 o;
#pragma unroll
        for (int i = 0; i < 4; ++i) o[i] = f2bf(t[d + i][e]);
        *(u16x4*)&dst[idx] = o;
    }
}

// ---------------------------------------------------------------------------
// MFMA bf16 GEMM (m97 structure): C[m,n] = sum_k A[m,k]*B[n,k]
// MODE 0: f32 out (no act). MODE 1: qkv fused, bf16 out, elu1 on seg 0/1.
// ---------------------------------------------------------------------------
template <int MODE>
__global__ __launch_bounds__(256) void gemm_mfma_kernel(const unsigned short* __restrict__ A,
                                                        const unsigned short* __restrict__ B,
                                                        float* __restrict__ f32out,
                                                        unsigned short* __restrict__ b0,
                                                        unsigned short* __restrict__ b1,
                                                        unsigned short* __restrict__ b2,
                                                        int K) {
    __shared__ unsigned short Als[128][32];
    __shared__ unsigned short Bls[128][32];
    const int tid  = threadIdx.x;
    const int lane = tid & 63;
    const int wv   = tid >> 6;
    const int wr   = wv >> 1;
    const int wc   = wv & 1;
    const int bm   = blockIdx.x * 128;
    const int bn   = blockIdx.y * 128;

    const int srow = (wv << 5) + (lane >> 2);
    const int skc  = (lane & 3) << 3;
    const unsigned short* gA = A + (size_t)(bm + srow) * K + skc;
    const unsigned short* gB = B + (size_t)(bn + srow) * K + skc;

    const int frow = lane & 15;
    const int fkof = (lane >> 4) << 3;

    f32x4 acc[4][4] = {};

    for (int k0 = 0; k0 < K; k0 += 32) {
        __syncthreads();
        __builtin_amdgcn_global_load_lds(
            (const __attribute__((address_space(1))) void*)(gA + k0),
            (__attribute__((address_space(3))) void*)&Als[(wv << 5)][0], 16, 0, 0);
        __builtin_amdgcn_global_load_lds(
            (const __attribute__((address_space(1))) void*)(gA + k0 + 16 * (size_t)K),
            (__attribute__((address_space(3))) void*)&Als[(wv << 5) + 16][0], 16, 0, 0);
        __builtin_amdgcn_global_load_lds(
            (const __attribute__((address_space(1))) void*)(gB + k0),
            (__attribute__((address_space(3))) void*)&Bls[(wv << 5)][0], 16, 0, 0);
        __builtin_amdgcn_global_load_lds(
            (const __attribute__((address_space(1))) void*)(gB + k0 + 16 * (size_t)K),
            (__attribute__((address_space(3))) void*)&Bls[(wv << 5) + 16][0], 16, 0, 0);
        __syncthreads();

        bf16x8 af[4], bf[4];
#pragma unroll
        for (int mi = 0; mi < 4; ++mi)
            af[mi] = *(const bf16x8*)&Als[wr * 64 + mi * 16 + frow][fkof];
#pragma unroll
        for (int ni = 0; ni < 4; ++ni)
            bf[ni] = *(const bf16x8*)&Bls[wc * 64 + ni * 16 + frow][fkof];
#pragma unroll
        for (int mi = 0; mi < 4; ++mi)
#pragma unroll
            for (int ni = 0; ni < 4; ++ni)
                acc[mi][ni] = __builtin_amdgcn_mfma_f32_16x16x32_bf16(af[mi], bf[ni], acc[mi][ni], 0, 0, 0);
    }

    unsigned short* bdst = b0;
    int colbase = bn;
    bool act = false;
    if (MODE == 1) {
        const int seg = bn >> 10;
        bdst = (seg == 0) ? b0 : ((seg == 1) ? b1 : b2);
        colbase = bn & 1023;
        act = (seg < 2);
    }
    const int crow = (lane >> 4) << 2;
    const int ccol = lane & 15;
#pragma unroll
    for (int mi = 0; mi < 4; ++mi) {
#pragma unroll
        for (int ni = 0; ni < 4; ++ni) {
            const int col = colbase + wc * 64 + ni * 16 + ccol;
#pragma unroll
            for (int r = 0; r < 4; ++r) {
                const int row = bm + wr * 64 + mi * 16 + crow + r;
                float x = acc[mi][ni][r];
                if (MODE == 0) {
                    f32out[(size_t)row * 1024 + col] = x;
                } else {
                    if (act) x = (x > 0.f) ? (x + 1.f) : __expf(x);
                    bdst[(size_t)row * 1024 + col] = f2bf(x);
                }
            }
        }
    }
}

// ---------------------------------------------------------------------------
// rel[m,h,s] = sum_d qb[s, h*64+d] * norms[m,h,d];  relsum[m,h] = sum_s rel
// ---------------------------------------------------------------------------
__global__ __launch_bounds__(256) void rel_kernel(const unsigned short* __restrict__ qb,
                                                  const float* __restrict__ norms,
                                                  float* __restrict__ rel,
                                                  float* __restrict__ relsum) {
    const int m = blockIdx.x >> 4;
    const int h = blockIdx.x & 15;
    __shared__ float nl[64];
    __shared__ float red[256];
    const int tid = threadIdx.x;
    if (tid < 64) nl[tid] = norms[(size_t)(m * NHEAD + h) * HD + tid];
    __syncthreads();
    float lsum = 0.f;
    for (int s = tid; s < S_LEN; s += 256) {
        const unsigned short* row = qb + (size_t)s * H_DIM + h * HD;
        float dot = 0.f;
#pragma unroll
        for (int d = 0; d < 64; d += 8) {
            u16x8 v = *(const u16x8*)(row + d);
#pragma unroll
            for (int i = 0; i < 8; ++i) dot += bf2f(v[i]) * nl[d + i];
        }
        rel[(size_t)(m * NHEAD + h) * S_LEN + s] = dot;
        lsum += dot;
    }
    red[tid] = lsum;
    __syncthreads();
    for (int o = 128; o > 0; o >>= 1) {
        if (tid < o) red[tid] += red[tid + o];
        __syncthreads();
    }
    if (tid == 0) relsum[m * NHEAD + h] = red[0];
}

__global__ void weights_kernel(const float* __restrict__ relsum,
                               float* __restrict__ weights) {
    const int h = threadIdx.x;
    if (h >= NHEAD) return;
    float v[NMEM];
    float mx = -1e30f;
#pragma unroll
    for (int m = 0; m < NMEM; ++m) {
        v[m] = relsum[m * NHEAD + h] / (float)S_LEN;
        mx = fmaxf(mx, v[m]);
    }
    float sum = 0.f;
#pragma unroll
    for (int m = 0; m < NMEM; ++m) { v[m] = __expf(v[m] - mx); sum += v[m]; }
#pragma unroll
    for (int m = 0; m < NMEM; ++m) weights[m * NHEAD + h] = v[m] / sum;
}

// ---------------------------------------------------------------------------
// ckvT[h,c,e,d] = sum_{s in chunk} v[s,e]*k[s,d];  cks[h,c,d] = sum k[s,d]
// ---------------------------------------------------------------------------
__global__ __launch_bounds__(256) void chunkkv_kernel(const unsigned short* __restrict__ vb,
                                                      const unsigned short* __restrict__ kb,
                                                      float* __restrict__ ckvT,
                                                      float* __restrict__ cks) {
    const int h = blockIdx.x;
    const int c = blockIdx.y;
    const int s0 = c * CLEN;
    __shared__ float vs[64][64];
    __shared__ float ks[64][64];
    const int tid = threadIdx.x;
#pragma unroll
    for (int j = 0; j < 2; ++j) {
        const int idx = j * 2048 + tid * 8;
        const int r = idx >> 6, cc = idx & 63;
        u16x8 v8 = *(const u16x8*)&vb[(size_t)(s0 + r) * H_DIM + h * HD + cc];
        u16x8 k8 = *(const u16x8*)&kb[(size_t)(s0 + r) * H_DIM + h * HD + cc];
#pragma unroll
        for (int i = 0; i < 8; ++i) {
            vs[r][cc + i] = bf2f(v8[i]);
            ks[r][cc + i] = bf2f(k8[i]);
        }
    }
    __syncthreads();
    const int d = tid & 63;
    const int eb = (tid >> 6) * 16;
    float acc[16] = {};
    for (int s = 0; s < 64; ++s) {
        const float kv = ks[s][d];
#pragma unroll
        for (int i = 0; i < 16; ++i) acc[i] = fmaf(vs[s][eb + i], kv, acc[i]);
    }
    float* outp = ckvT + (size_t)(h * NCHUNK + c) * HD * HD;
#pragma unroll
    for (int i = 0; i < 16; ++i) outp[(eb + i) * 64 + d] = acc[i];
    if (tid < 64) {
        float sksum = 0.f;
        for (int s = 0; s < 64; ++s) sksum += ks[s][tid];
        cks[(size_t)(h * NCHUNK + c) * HD + tid] = sksum;
    }
}

// ---------------------------------------------------------------------------
// Exclusive prefix over chunks. grid (NHEAD, 4), 256 threads
// ---------------------------------------------------------------------------
__global__ __launch_bounds__(256) void prefix_kernel(float* __restrict__ ckvT,
                                                     float* __restrict__ cks) {
    const int h = blockIdx.x;
    const int g = blockIdx.y;
    const int tid = threadIdx.x;
    const int d = tid & 63;
    const int e0 = g * 16 + (tid >> 6) * 4;
    float run[4] = {0.f, 0.f, 0.f, 0.f};
    for (int c = 0; c < NCHUNK; ++c) {
        float* base = ckvT + (size_t)(h * NCHUNK + c) * 4096;
#pragma unroll
        for (int i = 0; i < 4; ++i) {
            float* p = base + (e0 + i) * 64 + d;
            const float cur = *p;
            *p = run[i];
            run[i] += cur;
        }
    }
    if (g == 0 && tid < 64) {
        float rk = 0.f;
        for (int c = 0; c < NCHUNK; ++c) {
            float* p = cks + (size_t)(h * NCHUNK + c) * HD + tid;
            const float cur = *p;
            *p = rk;
            rk += cur;
        }
    }
}

// ---------------------------------------------------------------------------
// Fused output kernel for one (head, chunk): memory retrieval + causal local
// attention, all MFMA. Writes cb bf16 (input to the final GEMM).
//   local[s,e] = (P@V + Q@KVpre)[s,e] / den[s]
//   mem[s,e]   = sum_m c[m,s] * (Q @ M_m^T)[s,e],  c = w_m/max(rel,eps)
//   cb[s,e]    = bf16( g*mem + (1-g)*local )
// ---------------------------------------------------------------------------
__global__ __launch_bounds__(256) void fused_out_kernel(const unsigned short* __restrict__ qb,
                                                        const unsigned short* __restrict__ kb,
                                                        const unsigned short* __restrict__ vb,
                                                        const float* __restrict__ ckvT,
                                                        const float* __restrict__ cks,
                                                        const unsigned short* __restrict__ mbT,
                                                        const float* __restrict__ rel,
                                                        const float* __restrict__ weights,
                                                        const float* __restrict__ gate,
                                                        unsigned short* __restrict__ cb) {
    const int h = blockIdx.x;
    const int c = blockIdx.y;
    const int s0 = c * CLEN;
    __shared__ unsigned short Qs[4096], Ks[4096], VsT[4096], KVsT[4096], Ps[4096];
    __shared__ unsigned short Ms[4][4096];
    __shared__ float kp_lds[64];
    __shared__ float den_lds[64];
    __shared__ float c_lds[4][64];
    char* Qb  = (char*)Qs;
    char* Kb  = (char*)Ks;
    char* Vb  = (char*)VsT;
    char* KVb = (char*)KVsT;
    char* Pb  = (char*)Ps;
    const int tid = threadIdx.x;
    const int lane = tid & 63;
    const int w = tid >> 6;

#define SWZ(row, colbyte) ((row) * 128 + ((colbyte) ^ (((row) & 7) << 4)))

    // --- stage Q, K (row-major), V (transposed) ---
#pragma unroll
    for (int p = 0; p < 2; ++p) {
        const int idx = p * 2048 + tid * 8;
        const int r = idx >> 6, cc = idx & 63;
        const size_t gidx = (size_t)(s0 + r) * H_DIM + h * HD + cc;
        u16x8 q8 = *(const u16x8*)&qb[gidx];
        u16x8 k8 = *(const u16x8*)&kb[gidx];
        u16x8 v8 = *(const u16x8*)&vb[gidx];
        *(u16x8*)(Qb + SWZ(r, cc * 2)) = q8;
        *(u16x8*)(Kb + SWZ(r, cc * 2)) = k8;
#pragma unroll
        for (int j = 0; j < 8; ++j)
            *(unsigned short*)(Vb + SWZ(cc + j, r * 2)) = (unsigned short)v8[j];
    }
    // --- stage KV^T (f32 -> bf16; ckvT already [e][d]) ---
    const float* kvsrc = ckvT + (size_t)(h * NCHUNK + c) * 4096;
#pragma unroll
    for (int p = 0; p < 4; ++p) {
        const int idx = p * 1024 + tid * 4;
        const int e = idx >> 6, d = idx & 63;
        float4 f = *(const float4*)&kvsrc[idx];
        u16x4 o4;
        o4[0] = f2bf(f.x); o4[1] = f2bf(f.y); o4[2] = f2bf(f.z); o4[3] = f2bf(f.w);
        *(u16x4*)(KVb + SWZ(e, d * 2)) = o4;
    }
    // --- stage memories (bf16, already [e][d]) ---
#pragma unroll
    for (int m = 0; m < NMEM; ++m) {
        const unsigned short* msrc = mbT + (size_t)(m * NHEAD + h) * 4096;
        char* Mb = (char*)Ms[m];
#pragma unroll
        for (int p = 0; p < 2; ++p) {
            const int idx = p * 2048 + tid * 8;
            const int e = idx >> 6, d = idx & 63;
            *(u16x8*)(Mb + SWZ(e, d * 2)) = *(const u16x8*)&msrc[idx];
        }
    }
    if (tid < 64) kp_lds[tid] = cks[(size_t)(h * NCHUNK + c) * HD + tid];
    {
        const int m = tid >> 6, si = tid & 63;
        c_lds[m][si] = weights[m * NHEAD + h] /
                       fmaxf(rel[(size_t)(m * NHEAD + h) * S_LEN + s0 + si], EPS_C);
    }
    __syncthreads();

    // --- den_init[s] = q[s]·kpre ---
    {
        const int s = tid >> 2, part = tid & 3;
        float acc = 0.f;
#pragma unroll
        for (int j = 0; j < 16; ++j) {
            const int d = part * 16 + j;
            acc += bf2f(*(unsigned short*)(Qb + SWZ(s, d * 2))) * kp_lds[d];
        }
        acc += __shfl_xor(acc, 1);
        acc += __shfl_xor(acc, 2);
        if (part == 0) den_lds[s] = acc;
    }

    // --- QK^T ---
    const int sb = w * 16;
    const int fr = lane & 15;
    const int fk = (lane >> 4) * 8;
    bf16x8 aq0 = *(bf16x8*)(Qb + SWZ(sb + fr, fk * 2));
    bf16x8 aq1 = *(bf16x8*)(Qb + SWZ(sb + fr, (32 + fk) * 2));
    f32x4 aqk[4] = {};
#pragma unroll
    for (int nt = 0; nt < 4; ++nt) {
        bf16x8 bk0 = *(bf16x8*)(Kb + SWZ(nt * 16 + fr, fk * 2));
        bf16x8 bk1 = *(bf16x8*)(Kb + SWZ(nt * 16 + fr, (32 + fk) * 2));
        aqk[nt] = __builtin_amdgcn_mfma_f32_16x16x32_bf16(aq0, bk0, aqk[nt], 0, 0, 0);
        aqk[nt] = __builtin_amdgcn_mfma_f32_16x16x32_bf16(aq1, bk1, aqk[nt], 0, 0, 0);
    }
    // mask (t<=s), write P bf16, accumulate row sums
    float rs[4] = {0.f, 0.f, 0.f, 0.f};
    const int srow0 = sb + (lane >> 4) * 4;
#pragma unroll
    for (int nt = 0; nt < 4; ++nt) {
        const int t = nt * 16 + fr;
#pragma unroll
        for (int r = 0; r < 4; ++r) {
            const int s = srow0 + r;
            const float pv = (t <= s) ? aqk[nt][r] : 0.f;
            rs[r] += pv;
            *(unsigned short*)(Pb + SWZ(s, t * 2)) = f2bf(pv);
        }
    }
#pragma unroll
    for (int m = 1; m < 16; m <<= 1) {
        rs[0] += __shfl_xor(rs[0], m);
        rs[1] += __shfl_xor(rs[1], m);
        rs[2] += __shfl_xor(rs[2], m);
        rs[3] += __shfl_xor(rs[3], m);
    }
    if (fr == 0) {
#pragma unroll
        for (int r = 0; r < 4; ++r) den_lds[srow0 + r] += rs[r];
    }
    __syncthreads();

    // --- num = P@V + Q@KVpre; mem = sum_m c_m * (Q@M_m^T); epilogue ---
    const float g = 1.f / (1.f + __expf(-gate[h]));
    const float gl = 1.f - g;
#pragma unroll
    for (int nt = 0; nt < 4; ++nt) {
        const int br = nt * 16 + fr;
        f32x4 lacc = {};
        bf16x8 ap0 = *(bf16x8*)(Pb + SWZ(sb + fr, fk * 2));
        bf16x8 ap1 = *(bf16x8*)(Pb + SWZ(sb + fr, (32 + fk) * 2));
        bf16x8 bv0 = *(bf16x8*)(Vb + SWZ(br, fk * 2));
        bf16x8 bv1 = *(bf16x8*)(Vb + SWZ(br, (32 + fk) * 2));
        lacc = __builtin_amdgcn_mfma_f32_16x16x32_bf16(ap0, bv0, lacc, 0, 0, 0);
        lacc = __builtin_amdgcn_mfma_f32_16x16x32_bf16(ap1, bv1, lacc, 0, 0, 0);
        bf16x8 bkv0 = *(bf16x8*)(KVb + SWZ(br, fk * 2));
        bf16x8 bkv1 = *(bf16x8*)(KVb + SWZ(br, (32 + fk) * 2));
        lacc = __builtin_amdgcn_mfma_f32_16x16x32_bf16(aq0, bkv0, lacc, 0, 0, 0);
        lacc = __builtin_amdgcn_mfma_f32_16x16x32_bf16(aq1, bkv1, lacc, 0, 0, 0);

        f32x4 macc = {};
#pragma unroll
        for (int m = 0; m < NMEM; ++m) {
            char* Mb = (char*)Ms[m];
            bf16x8 bm0 = *(bf16x8*)(Mb + SWZ(br, fk * 2));
            bf16x8 bm1 = *(bf16x8*)(Mb + SWZ(br, (32 + fk) * 2));
            f32x4 mm = {};
            mm = __builtin_amdgcn_mfma_f32_16x16x32_bf16(aq0, bm0, mm, 0, 0, 0);
            mm = __builtin_amdgcn_mfma_f32_16x16x32_bf16(aq1, bm1, mm, 0, 0, 0);
#pragma unroll
            for (int r = 0; r < 4; ++r)
                macc[r] = fmaf(c_lds[m][srow0 + r], mm[r], macc[r]);
        }

        const int e = nt * 16 + fr;
#pragma unroll
        for (int r = 0; r < 4; ++r) {
            const int s = srow0 + r;
            const float den = fmaxf(den_lds[s], EPS_C);
            const float val = g * macc[r] + gl * lacc[r] / den;
            cb[(size_t)(s0 + s) * H_DIM + h * HD + e] = f2bf(val);
        }
    }
#undef SWZ
}

extern "C" void kernel_launch(void* const* d_in, const int* in_sizes, int n_in,
                              void* d_out, int out_size, void* d_ws, size_t ws_size,
                              hipStream_t stream) {
    const float* hidden   = (const float*)d_in[0];
    const float* w_q      = (const float*)d_in[1];
    const float* w_k      = (const float*)d_in[2];
    const float* w_v      = (const float*)d_in[3];
    const float* w_o      = (const float*)d_in[4];
    const float* gate     = (const float*)d_in[5];
    const float* memories = (const float*)d_in[6];
    const float* memnorms = (const float*)d_in[7];
    float* out = (float*)d_out;

    float* ws = (float*)d_ws;
    size_t off = 0;
    float* rel      = ws + off; off += (size_t)NMEM * NHEAD * S_LEN;
    float* relsum   = ws + off; off += NMEM * NHEAD;
    float* weights  = ws + off; off += 64;
    float* ckvT     = ws + off; off += (size_t)NHEAD * NCHUNK * HD * HD;
    float* cks      = ws + off; off += (size_t)NHEAD * NCHUNK * HD;
    unsigned short* hb  = (unsigned short*)(ws + off); off += (size_t)S_LEN * H_DIM / 2;
    unsigned short* wb  = (unsigned short*)(ws + off); off += (size_t)3 * H_DIM * H_DIM / 2;
    unsigned short* wob = (unsigned short*)(ws + off); off += (size_t)H_DIM * H_DIM / 2;
    unsigned short* qb  = (unsigned short*)(ws + off); off += (size_t)S_LEN * H_DIM / 2;
    unsigned short* kb  = (unsigned short*)(ws + off); off += (size_t)S_LEN * H_DIM / 2;
    unsigned short* vb  = (unsigned short*)(ws + off); off += (size_t)S_LEN * H_DIM / 2;
    unsigned short* cb  = (unsigned short*)(ws + off); off += (size_t)S_LEN * H_DIM / 2;
    unsigned short* mbT = (unsigned short*)(ws + off); off += (size_t)NMEM * NHEAD * HD * HD / 2;

    // --- input conversions + memory transpose ---
    cvt_bf16_kernel<<<S_LEN * H_DIM / 2048, 256, 0, stream>>>(hidden, hb);
    cvt_bf16_kernel<<<H_DIM * H_DIM / 2048, 256, 0, stream>>>(w_q, wb);
    cvt_bf16_kernel<<<H_DIM * H_DIM / 2048, 256, 0, stream>>>(w_k, wb + (size_t)H_DIM * H_DIM);
    cvt_bf16_kernel<<<H_DIM * H_DIM / 2048, 256, 0, stream>>>(w_v, wb + (size_t)2 * H_DIM * H_DIM);
    cvt_bf16_kernel<<<H_DIM * H_DIM / 2048, 256, 0, stream>>>(w_o, wob);
    memT_kernel<<<NMEM * NHEAD, 256, 0, stream>>>(memories, mbT);

    // --- fused QKV projection -> q/k/v bf16 ---
    gemm_mfma_kernel<1><<<dim3(S_LEN / 128, 3 * H_DIM / 128), 256, 0, stream>>>(
        hb, wb, nullptr, qb, kb, vb, H_DIM);

    // --- memory-selection weights ---
    rel_kernel<<<NMEM * NHEAD, 256, 0, stream>>>(qb, memnorms, rel, relsum);
    weights_kernel<<<1, 64, 0, stream>>>(relsum, weights);

    // --- causal linear attention state ---
    chunkkv_kernel<<<dim3(NHEAD, NCHUNK), 256, 0, stream>>>(vb, kb, ckvT, cks);
    prefix_kernel<<<dim3(NHEAD, 4), 256, 0, stream>>>(ckvT, cks);

    // --- fused memory + local output ---
    fused_out_kernel<<<dim3(NHEAD, NCHUNK), 256, 0, stream>>>(
        qb, kb, vb, ckvT, cks, mbT, rel, weights, gate, cb);

    // --- output projection ---
    gemm_mfma_kernel<0><<<dim3(S_LEN / 128, H_DIM / 128), 256, 0, stream>>>(
        cb, wob, out, nullptr, nullptr, nullptr, H_DIM);
}